// Round 7
// baseline (625.129 us; speedup 1.0000x reference)
//
#include <hip/hip_runtime.h>
#include <math.h>

// Problem constants
#define BATCH 8192
#define NFEAT 256
#define NH1   100     // fc1 width (K of fc2)
#define NH2   50      // fc2 width (N of fc2)
#define KP    128     // K padded: 4 MFMA k-steps of 32
#define NP    64      // N padded: 4 n-tiles of 16

typedef __attribute__((ext_vector_type(8))) _Float16 half8;   // 8 f16 (4 VGPRs)
typedef __attribute__((ext_vector_type(2))) __fp16   fp16x2;  // cvt_pkrtz result
typedef __attribute__((ext_vector_type(4))) float float4v;    // MFMA acc

// ---- workspace layout (fp32 units from ws start) ----
// w2h : NFEAT*16*64*8 f16 = 4 MB (fragment-ordered, zero-padded)
// w1p/b1p : NFEAT*KP fp32 ; b2p/w3p : NFEAT*NP fp32 ; ticket : 1 u32
#define W2H_ELEMS  (NFEAT * 16 * 64 * 8)
#define OFF_W1P    (W2H_ELEMS / 2)
#define OFF_B1P    (OFF_W1P + NFEAT * KP)
#define OFF_B2P    (OFF_B1P + NFEAT * KP)
#define OFF_W3P    (OFF_B2P + NFEAT * NP)
#define OFF_TKT    (OFF_W3P + NFEAT * NP)

// ---- pre-pass: one block per feature. Pads+converts weights, zeroes this
// feature's 32-row slice of out, block 0 zeroes the completion ticket.
__global__ __launch_bounds__(256) void prep(
    const float* __restrict__ W1, const float* __restrict__ b1,
    const float* __restrict__ W2, const float* __restrict__ b2,
    const float* __restrict__ W3, float* __restrict__ ws,
    float* __restrict__ out)
{
    const int f = blockIdx.x;
    const int t = threadIdx.x;
    float* w1p = ws + OFF_W1P + f * KP;
    float* b1p = ws + OFF_B1P + f * KP;
    float* b2p = ws + OFF_B2P + f * NP;
    float* w3p = ws + OFF_W3P + f * NP;
    _Float16* w2h = (_Float16*)ws + (size_t)f * (16 * 64 * 8);

    if (t < KP) {
        w1p[t] = (t < NH1) ? W1[f * NH1 + t] : 0.f;
        b1p[t] = (t < NH1) ? b1[f * NH1 + t] : 0.f;
    }
    if (t < NP)          b2p[t]      = (t < NH2)      ? b2[f * NH2 + t] : 0.f;
    else if (t < 2 * NP) w3p[t - NP] = (t - NP < NH2) ? W3[f * NH2 + (t - NP)] : 0.f;
    if (t < 32) out[f * 32 + t] = 0.f;
    if (f == 0 && t == 0) ((unsigned*)(ws + OFF_TKT))[0] = 0u;

    // w2h[f][kk][nt][lane][j] = f16(W2[f][o=16*nt+(lane&15)][h=32*kk+8*(lane>>4)+j])
    const float* w2g = W2 + (size_t)f * NH2 * NH1;
#pragma unroll
    for (int i = 0; i < 32; ++i) {
        const int e    = i * 256 + t;        // 0..8191
        const int j    = e & 7;
        const int lane = (e >> 3) & 63;
        const int nt   = (e >> 9) & 3;
        const int kk   = e >> 11;
        const int o    = nt * 16 + (lane & 15);
        const int h    = kk * 32 + (lane >> 4) * 8 + j;
        w2h[e] = (_Float16)((o < NH2 && h < NH1) ? w2g[o * NH1 + h] : 0.f);
    }
}

// ---- main: one wave = (64 batch rows, one feature). No LDS tiles/barriers
// in the hot path. B-fragments loaded per k-step (16 VGPRs live, not 64) so
// 3 waves/SIMD fit; fc1 -> fp16 A-fragments in-register (cvt_pkrtz).
// Last finished block applies bias+sigmoid (fused nam_finish).
__global__ __launch_bounds__(256, 3) void nam_mfma(
    const float* __restrict__ x,
    float* ws, float* out, const float* __restrict__ bias)
{
    const int t  = threadIdx.x;
    const int wv = t >> 6;
    const int ln = t & 15;
    const int qd = (t >> 4) & 3;
    const int f  = blockIdx.y * 4 + wv;
    const int b0 = blockIdx.x * 64;

    const float* w1p = ws + OFF_W1P + f * KP;
    const float* b1p = ws + OFF_B1P + f * KP;
    const _Float16* w2h =
        (const _Float16*)ws + (size_t)f * (16 * 64 * 8) + (t & 63) * 8;

    // x read directly (no transpose pass): 16 distinct lines per mt, L2/L3-served.
    float xv[4];
#pragma unroll
    for (int mt = 0; mt < 4; ++mt)
        xv[mt] = x[(size_t)(b0 + mt * 16 + ln) * NFEAT + f];

    float4v acc[4][4];
#pragma unroll
    for (int mt = 0; mt < 4; ++mt)
#pragma unroll
        for (int nt = 0; nt < 4; ++nt) acc[mt][nt] = (float4v){0.f, 0.f, 0.f, 0.f};

#pragma unroll
    for (int kk = 0; kk < 4; ++kk) {
        // this k-step's 4 B-fragments (1KB coalesced each)
        half8 bf[4];
#pragma unroll
        for (int nt = 0; nt < 4; ++nt)
            bf[nt] = *(const half8*)(w2h + (kk * 4 + nt) * 512);

        const int kbase = kk * 32 + qd * 8;
        const float4 w0 = *(const float4*)(w1p + kbase);
        const float4 w1 = *(const float4*)(w1p + kbase + 4);
        const float4 c0 = *(const float4*)(b1p + kbase);
        const float4 c1 = *(const float4*)(b1p + kbase + 4);

#pragma unroll
        for (int mt = 0; mt < 4; ++mt) {
            const float xm = xv[mt];
            float a[8];
            a[0] = fmaxf(0.f, fmaf(xm, w0.x, c0.x));
            a[1] = fmaxf(0.f, fmaf(xm, w0.y, c0.y));
            a[2] = fmaxf(0.f, fmaf(xm, w0.z, c0.z));
            a[3] = fmaxf(0.f, fmaf(xm, w0.w, c0.w));
            a[4] = fmaxf(0.f, fmaf(xm, w1.x, c1.x));
            a[5] = fmaxf(0.f, fmaf(xm, w1.y, c1.y));
            a[6] = fmaxf(0.f, fmaf(xm, w1.z, c1.z));
            a[7] = fmaxf(0.f, fmaf(xm, w1.w, c1.w));

            half8 af;
            fp16x2* ap = (fp16x2*)&af;
            ap[0] = __builtin_amdgcn_cvt_pkrtz(a[0], a[1]);
            ap[1] = __builtin_amdgcn_cvt_pkrtz(a[2], a[3]);
            ap[2] = __builtin_amdgcn_cvt_pkrtz(a[4], a[5]);
            ap[3] = __builtin_amdgcn_cvt_pkrtz(a[6], a[7]);

#pragma unroll
            for (int nt = 0; nt < 4; ++nt)
                acc[mt][nt] = __builtin_amdgcn_mfma_f32_16x16x32_f16(
                    af, bf[nt], acc[mt][nt], 0, 0, 0);
        }
    }

    // ---- epilogue: h2 = relu(acc + b2); contrib = h2 . w3; reduce over o ----
    const float* b2p = ws + OFF_B2P + f * NP;
    const float* w3p = ws + OFF_W3P + f * NP;

    float rp[4][4] = {{0.f}, {0.f}, {0.f}, {0.f}};
#pragma unroll
    for (int nt = 0; nt < 4; ++nt) {
        const float bo = b2p[nt * 16 + ln];
        const float wo = w3p[nt * 16 + ln];
#pragma unroll
        for (int mt = 0; mt < 4; ++mt)
#pragma unroll
            for (int r = 0; r < 4; ++r)
                rp[mt][r] = fmaf(fmaxf(acc[mt][nt][r] + bo, 0.f), wo, rp[mt][r]);
    }
#pragma unroll
    for (int mt = 0; mt < 4; ++mt)
#pragma unroll
        for (int r = 0; r < 4; ++r) {
            float v = rp[mt][r];
            v += __shfl_xor(v, 1);
            v += __shfl_xor(v, 2);
            v += __shfl_xor(v, 4);
            v += __shfl_xor(v, 8);
            if (ln == 0)
                atomicAdd(out + b0 + mt * 16 + qd * 4 + r, v);  // C row = qd*4+r
        }

    // ---- fused finish: last block through the ticket does bias+sigmoid ----
    __shared__ int last;
    __threadfence();
    __syncthreads();                     // all waves' atomics issued + fenced
    if (t == 0) {
        unsigned* tkt = (unsigned*)(ws + OFF_TKT);
        last = (atomicAdd(tkt, 1u) == (unsigned)(gridDim.x * gridDim.y - 1));
    }
    __syncthreads();
    if (last) {
        const float bb = bias[0];
#pragma unroll
        for (int i = 0; i < BATCH / 256; ++i) {
            const int b = i * 256 + t;
            const float v = atomicAdd(out + b, 0.0f) + bb;  // L1-bypassing read
            out[b] = 1.0f / (1.0f + expf(-v));
        }
    }
}

extern "C" void kernel_launch(void* const* d_in, const int* in_sizes, int n_in,
                              void* d_out, int out_size, void* d_ws, size_t ws_size,
                              hipStream_t stream) {
    const float* x    = (const float*)d_in[0];
    const float* W1   = (const float*)d_in[1];
    const float* b1   = (const float*)d_in[2];
    const float* W2   = (const float*)d_in[3];
    const float* b2   = (const float*)d_in[4];
    const float* W3   = (const float*)d_in[5];
    const float* bias = (const float*)d_in[6];
    float* out = (float*)d_out;
    float* ws  = (float*)d_ws;   // ~4.4 MB used

    prep<<<NFEAT, 256, 0, stream>>>(W1, b1, W2, b2, W3, ws, out);

    nam_mfma<<<dim3(BATCH / 64, NFEAT / 4), 256, 0, stream>>>(x, ws, out, bias);
}

// Round 9
// 161.597 us; speedup vs baseline: 3.8684x; 3.8684x over previous
//
#include <hip/hip_runtime.h>
#include <math.h>

// Problem constants
#define BATCH 8192
#define NFEAT 256
#define NH1   100     // fc1 width (K of fc2)
#define NH2   50      // fc2 width (N of fc2)
#define KP    128     // K padded: 4 MFMA k-steps of 32
#define NP    64      // N padded: 4 n-tiles of 16

typedef __attribute__((ext_vector_type(8))) _Float16 half8;   // 8 f16 (4 VGPRs)
typedef __attribute__((ext_vector_type(2))) _Float16 h2v;     // packed fp16 pair
typedef __attribute__((ext_vector_type(4))) float float4v;    // MFMA acc

// ---- workspace layout (fp32 units from ws start) ----
// w2h : NFEAT*16*64*8 f16 = 4 MB (fragment-ordered, zero-padded)
// w1h/b1h : NFEAT*KP f16 ; b2p/w3p : NFEAT*NP fp32 ; xT : NFEAT*BATCH fp32
#define W2H_F32    (NFEAT * 16 * 64 * 8 / 2)
#define OFF_W1H    W2H_F32
#define OFF_B1H    (OFF_W1H + NFEAT * KP / 2)
#define OFF_B2P    (OFF_B1H + NFEAT * KP / 2)
#define OFF_W3P    (OFF_B2P + NFEAT * NP)
#define OFF_XT     (OFF_W3P + NFEAT * NP)

// ---- fused pre-pass ----
// blocks [0,NFEAT): pad+convert weights (W1/b1 -> fp16, W2 -> fragment-ordered
// fp16), zero this feature's out slice. blocks [NFEAT, NFEAT+512): 64x64
// transpose tiles of x -> xT.
__global__ __launch_bounds__(256) void prep(
    const float* __restrict__ x,
    const float* __restrict__ W1, const float* __restrict__ b1,
    const float* __restrict__ W2, const float* __restrict__ b2,
    const float* __restrict__ W3, float* __restrict__ ws,
    float* __restrict__ out)
{
    __shared__ float tile[64][65];
    const int bx = blockIdx.x;
    const int t  = threadIdx.x;

    if (bx < NFEAT) {
        const int f = bx;
        _Float16* w1h = (_Float16*)(ws + OFF_W1H) + f * KP;
        _Float16* b1h = (_Float16*)(ws + OFF_B1H) + f * KP;
        float* b2p = ws + OFF_B2P + f * NP;
        float* w3p = ws + OFF_W3P + f * NP;
        _Float16* w2h = (_Float16*)ws + (size_t)f * (16 * 64 * 8);

        if (t < KP) {
            w1h[t] = (_Float16)((t < NH1) ? W1[f * NH1 + t] : 0.f);
            b1h[t] = (_Float16)((t < NH1) ? b1[f * NH1 + t] : 0.f);
        }
        if (t < NP)          b2p[t]      = (t < NH2)      ? b2[f * NH2 + t] : 0.f;
        else if (t < 2 * NP) w3p[t - NP] = (t - NP < NH2) ? W3[f * NH2 + (t - NP)] : 0.f;
        if (t < 32) out[f * 32 + t] = 0.f;

        // w2h[f][kk][nt][lane][j] = f16(W2[f][o=16*nt+(lane&15)][h=32*kk+8*(lane>>4)+j])
        const float* w2g = W2 + (size_t)f * NH2 * NH1;
#pragma unroll
        for (int i = 0; i < 32; ++i) {
            const int e    = i * 256 + t;        // 0..8191
            const int j    = e & 7;
            const int lane = (e >> 3) & 63;
            const int nt   = (e >> 9) & 3;
            const int kk   = e >> 11;
            const int o    = nt * 16 + (lane & 15);
            const int h    = kk * 32 + (lane >> 4) * 8 + j;
            w2h[e] = (_Float16)((o < NH2 && h < NH1) ? w2g[o * NH1 + h] : 0.f);
        }
    } else {
        const int i  = bx - NFEAT;
        const int b0 = (i & 127) * 64;
        const int f0 = (i >> 7) * 64;
        float* xT = ws + OFF_XT;
        const int c = t & 63, r0 = t >> 6;
#pragma unroll
        for (int k = 0; k < 16; ++k)
            tile[r0 + k * 4][c] = x[(size_t)(b0 + r0 + k * 4) * NFEAT + f0 + c];
        __syncthreads();
#pragma unroll
        for (int k = 0; k < 16; ++k)
            xT[(size_t)(f0 + r0 + k * 4) * BATCH + b0 + c] = tile[c][r0 + k * 4];
    }
}

// ---- main: one wave = (64 batch rows, 32 of 64 N-cols, one feature).
// N split over blockIdx.z halves acc AGPRs (32) -> more waves/SIMD; B-fragment
// L2 traffic per wave halves so total is unchanged. fc1 in packed fp16
// (v_pk_fma_f16 + v_pk_max_f16 via native _Float16 vectors). No LDS, no ticket.
__global__ __launch_bounds__(256, 4) void nam_mfma(
    const float* __restrict__ ws,
    float* __restrict__ out)
{
    const int t  = threadIdx.x;
    const int wv = t >> 6;
    const int ln = t & 15;
    const int qd = (t >> 4) & 3;
    const int f  = blockIdx.y * 4 + wv;
    const int b0 = blockIdx.x * 64;
    const int nz = blockIdx.z;           // which 32-wide N half

    const _Float16* w2h =
        (const _Float16*)ws + (size_t)f * (16 * 64 * 8) + (t & 63) * 8;
    const _Float16* w1hp = (const _Float16*)(ws + OFF_W1H) + f * KP;
    const _Float16* b1hp = (const _Float16*)(ws + OFF_B1H) + f * KP;
    const float* xTp = ws + OFF_XT + (size_t)f * BATCH + b0;

    // x values for the 4 m-tiles (coalesced 64B loads), broadcast to fp16 pair
    h2v xh[4];
#pragma unroll
    for (int mt = 0; mt < 4; ++mt) {
        const _Float16 xs = (_Float16)xTp[mt * 16 + ln];
        xh[mt] = (h2v){xs, xs};
    }

    const h2v z2 = (h2v){(_Float16)0.f, (_Float16)0.f};

    float4v acc[4][2];
#pragma unroll
    for (int mt = 0; mt < 4; ++mt)
#pragma unroll
        for (int i = 0; i < 2; ++i) acc[mt][i] = (float4v){0.f, 0.f, 0.f, 0.f};

#pragma unroll
    for (int kk = 0; kk < 4; ++kk) {
        // this k-step's 2 B-fragments for our N half (1KB coalesced each)
        const half8 bf0 = *(const half8*)(w2h + (kk * 4 + nz * 2 + 0) * 512);
        const half8 bf1 = *(const half8*)(w2h + (kk * 4 + nz * 2 + 1) * 512);

        const int kbase = kk * 32 + qd * 8;
        const h2v* wp = (const h2v*)(w1hp + kbase);
        const h2v* cp = (const h2v*)(b1hp + kbase);
        const h2v w0 = wp[0], w1 = wp[1], w2 = wp[2], w3 = wp[3];
        const h2v c0 = cp[0], c1 = cp[1], c2 = cp[2], c3 = cp[3];

#pragma unroll
        for (int mt = 0; mt < 4; ++mt) {
            half8 af;
            h2v* ap = (h2v*)&af;
            ap[0] = __builtin_elementwise_max(w0 * xh[mt] + c0, z2);
            ap[1] = __builtin_elementwise_max(w1 * xh[mt] + c1, z2);
            ap[2] = __builtin_elementwise_max(w2 * xh[mt] + c2, z2);
            ap[3] = __builtin_elementwise_max(w3 * xh[mt] + c3, z2);

            acc[mt][0] = __builtin_amdgcn_mfma_f32_16x16x32_f16(af, bf0, acc[mt][0], 0, 0, 0);
            acc[mt][1] = __builtin_amdgcn_mfma_f32_16x16x32_f16(af, bf1, acc[mt][1], 0, 0, 0);
        }
    }

    // ---- epilogue: h2 = relu(acc + b2); contrib = h2 . w3; reduce over o ----
    const float* b2p = ws + OFF_B2P + f * NP + nz * 32;
    const float* w3p = ws + OFF_W3P + f * NP + nz * 32;

    float rp[4][4] = {{0.f}, {0.f}, {0.f}, {0.f}};
#pragma unroll
    for (int i = 0; i < 2; ++i) {
        const float bo = b2p[i * 16 + ln];
        const float wo = w3p[i * 16 + ln];
#pragma unroll
        for (int mt = 0; mt < 4; ++mt)
#pragma unroll
            for (int r = 0; r < 4; ++r)
                rp[mt][r] = fmaf(fmaxf(acc[mt][i][r] + bo, 0.f), wo, rp[mt][r]);
    }
#pragma unroll
    for (int mt = 0; mt < 4; ++mt)
#pragma unroll
        for (int r = 0; r < 4; ++r) {
            float v = rp[mt][r];
            v += __shfl_xor(v, 1);
            v += __shfl_xor(v, 2);
            v += __shfl_xor(v, 4);
            v += __shfl_xor(v, 8);
            if (ln == 0)
                atomicAdd(out + b0 + mt * 16 + qd * 4 + r, v);  // C row = qd*4+r
        }
}

__global__ __launch_bounds__(256) void nam_finish(
    float* __restrict__ out, const float* __restrict__ bias)
{
    const int b = blockIdx.x * blockDim.x + threadIdx.x;
    out[b] = 1.0f / (1.0f + expf(-(out[b] + bias[0])));
}

extern "C" void kernel_launch(void* const* d_in, const int* in_sizes, int n_in,
                              void* d_out, int out_size, void* d_ws, size_t ws_size,
                              hipStream_t stream) {
    const float* x    = (const float*)d_in[0];
    const float* W1   = (const float*)d_in[1];
    const float* b1   = (const float*)d_in[2];
    const float* W2   = (const float*)d_in[3];
    const float* b2   = (const float*)d_in[4];
    const float* W3   = (const float*)d_in[5];
    const float* bias = (const float*)d_in[6];
    float* out = (float*)d_out;
    float* ws  = (float*)d_ws;   // ~12.5 MB used

    prep<<<NFEAT + (BATCH / 64) * (NFEAT / 64), 256, 0, stream>>>(
        x, W1, b1, W2, b2, W3, ws, out);

    nam_mfma<<<dim3(BATCH / 64, NFEAT / 4, 2), 256, 0, stream>>>(ws, out);

    nam_finish<<<BATCH / 256, 256, 0, stream>>>(out, bias);
}